// Round 6
// baseline (588.047 us; speedup 1.0000x reference)
//
#include <hip/hip_runtime.h>
#include <hip/hip_bf16.h>

#define B_ 4
#define S_ 2048
#define M_ 2048
#define H_ 16
#define D_ 128
#define ROWS (B_*S_)      // 8192
#define CQKV (3*H_*D_)    // 6144

typedef __bf16 bf16x8 __attribute__((ext_vector_type(8)));
typedef float f32x4 __attribute__((ext_vector_type(4)));
typedef unsigned short u16x8 __attribute__((ext_vector_type(8)));
typedef unsigned short u16x4 __attribute__((ext_vector_type(4)));

__device__ __forceinline__ unsigned short f2bf(float x) {
    unsigned u = __builtin_bit_cast(unsigned, x);
    u += 0x7fffu + ((u >> 16) & 1u);   // RNE
    return (unsigned short)(u >> 16);
}
__device__ __forceinline__ float bf2f(unsigned short u) {
    return __builtin_bit_cast(float, (unsigned)u << 16);
}

// async global->LDS, 16B per lane; LDS dest = base + lane*16 (wave-uniform base)
__device__ __forceinline__ void gld_lds16(const unsigned short* g, unsigned short* l) {
    __builtin_amdgcn_global_load_lds(
        (__attribute__((address_space(1))) void*)g,
        (__attribute__((address_space(3))) void*)l,
        16, 0, 0);
}

// ---------------- conversion kernels ----------------

__global__ __launch_bounds__(256) void cvt_bf16(const float* __restrict__ in,
                                                unsigned short* __restrict__ out) {
    int idx = (blockIdx.x * 256 + threadIdx.x) * 4;
    float4 v = *(const float4*)&in[idx];
    u16x4 o = { f2bf(v.x), f2bf(v.y), f2bf(v.z), f2bf(v.w) };
    *(u16x4*)&out[idx] = o;
}

// out[c*R + r] = bf16(in[r*C + c]);  grid = (C/32, R/32), block = (32,8)
__global__ __launch_bounds__(256) void cvt_transpose(const float* __restrict__ in,
                                                     unsigned short* __restrict__ out,
                                                     int R, int C) {
    __shared__ unsigned short tile[32][33];
    int c0 = blockIdx.x * 32, r0 = blockIdx.y * 32;
    int tx = threadIdx.x, ty = threadIdx.y;
#pragma unroll
    for (int i = 0; i < 4; ++i)
        tile[ty + i * 8][tx] = f2bf(in[(size_t)(r0 + ty + i * 8) * C + c0 + tx]);
    __syncthreads();
#pragma unroll
    for (int i = 0; i < 4; ++i)
        out[(size_t)(c0 + ty + i * 8) * R + r0 + tx] = tile[tx][ty + i * 8];
}

// ---------------- 256x256/BK64 8-phase GEMM core (T1+T2+T3+T4+T5) ----------------
// LDS: 2 buffers x (A[256][64] + B[256][64]) bf16 = 128 KiB.
// Staging: Ah0(u)@[u-1,A], Ah1(u)@[u-1,B], Bh0(u)@[u-2,C], Bh1(u)@[u-2,D];
// counted vmcnt(4) once per tile.  T2: chunk ^= row&7 via inverse-swizzled
// global source (linear LDS dest) + swizzled ds_read.

#define BM2 256
#define BN2 256
#define BK2 64
#define NT2 (M_/BK2)   // 32

#define STAGE(p_, u_, mat_, h_) do {                                                     \
        const unsigned short* _s = (mat_) ? Bg : Ag;                                     \
        const size_t _r = (size_t)((((mat_) ? c0 : r0) + (h_) * 128) + w * 8 + srow) * M_ \
                          + (u_) * BK2 + scol;                                           \
        unsigned short* _l = &lds[(p_) * 32768 + (mat_) * 16384 + (h_) * 8192 + w * 512]; \
        gld_lds16(&_s[_r], _l);                                                          \
        gld_lds16(&_s[_r + (size_t)64 * M_], _l + 4096);                                 \
    } while (0)

#define BAR() asm volatile("s_barrier" ::: "memory")

#define GEMM_MAIN_LOOP()                                                                  \
    const int srow = lane >> 3;                                                           \
    const int scol = ((lane & 7) ^ srow) * 8;                                             \
    const int axor = lcol & 7;                                                            \
    const int k0off = (lq ^ axor) * 8;                                                    \
    const int k1off = ((4 | lq) ^ axor) * 8;                                              \
    const int arow = wr * 8192 + lcol * 64;                                               \
    const int brow = 16384 + (wc >> 1) * 8192 + ((wc & 1) * 64 + lcol) * 64;              \
    f32x4 acc[8][4];                                                                      \
    _Pragma("unroll") for (int i = 0; i < 8; ++i)                                         \
        _Pragma("unroll") for (int j = 0; j < 4; ++j) acc[i][j] = (f32x4){0.f,0.f,0.f,0.f};\
    STAGE(0, 0, 0, 0); STAGE(0, 0, 0, 1); STAGE(0, 0, 1, 0); STAGE(0, 0, 1, 1);           \
    STAGE(1, 1, 1, 0); STAGE(1, 1, 1, 1);                                                 \
    asm volatile("s_waitcnt vmcnt(4)" ::: "memory");                                      \
    BAR();                                                                                \
    bf16x8 a[4][2], b[4][2];                                                              \
    for (int t = 0; t < NT2; ++t) {                                                       \
        const int bo = (t & 1) * 32768;                                                   \
        const int pn = (t + 1) & 1;                                                       \
        const int u1 = (t + 1 < NT2) ? (t + 1) : (NT2 - 1);                               \
        const int u2 = (t + 2 < NT2) ? (t + 2) : (NT2 - 1);                               \
        _Pragma("unroll") for (int i = 0; i < 4; ++i) {                                   \
            a[i][0] = *(const bf16x8*)&lds[bo + arow + i * 1024 + k0off];                  \
            a[i][1] = *(const bf16x8*)&lds[bo + arow + i * 1024 + k1off];                  \
        }                                                                                 \
        _Pragma("unroll") for (int j = 0; j < 2; ++j) {                                   \
            b[j][0] = *(const bf16x8*)&lds[bo + brow + j * 1024 + k0off];                  \
            b[j][1] = *(const bf16x8*)&lds[bo + brow + j * 1024 + k1off];                  \
        }                                                                                 \
        STAGE(pn, u1, 0, 0);                                                              \
        BAR();                                                                            \
        __builtin_amdgcn_s_setprio(1);                                                    \
        _Pragma("unroll") for (int i = 0; i < 4; ++i)                                     \
            _Pragma("unroll") for (int j = 0; j < 2; ++j) {                               \
                acc[i][j] = __builtin_amdgcn_mfma_f32_16x16x32_bf16(a[i][0], b[j][0], acc[i][j], 0, 0, 0); \
                acc[i][j] = __builtin_amdgcn_mfma_f32_16x16x32_bf16(a[i][1], b[j][1], acc[i][j], 0, 0, 0); \
            }                                                                             \
        __builtin_amdgcn_s_setprio(0);                                                    \
        BAR();                                                                            \
        _Pragma("unroll") for (int j = 2; j < 4; ++j) {                                   \
            b[j][0] = *(const bf16x8*)&lds[bo + brow + j * 1024 + k0off];                  \
            b[j][1] = *(const bf16x8*)&lds[bo + brow + j * 1024 + k1off];                  \
        }                                                                                 \
        STAGE(pn, u1, 0, 1);                                                              \
        BAR();                                                                            \
        __builtin_amdgcn_s_setprio(1);                                                    \
        _Pragma("unroll") for (int i = 0; i < 4; ++i)                                     \
            _Pragma("unroll") for (int j = 2; j < 4; ++j) {                               \
                acc[i][j] = __builtin_amdgcn_mfma_f32_16x16x32_bf16(a[i][0], b[j][0], acc[i][j], 0, 0, 0); \
                acc[i][j] = __builtin_amdgcn_mfma_f32_16x16x32_bf16(a[i][1], b[j][1], acc[i][j], 0, 0, 0); \
            }                                                                             \
        __builtin_amdgcn_s_setprio(0);                                                    \
        BAR();                                                                            \
        _Pragma("unroll") for (int i = 0; i < 4; ++i) {                                   \
            a[i][0] = *(const bf16x8*)&lds[bo + arow + (i + 4) * 1024 + k0off];            \
            a[i][1] = *(const bf16x8*)&lds[bo + arow + (i + 4) * 1024 + k1off];            \
        }                                                                                 \
        STAGE(t & 1, u2, 1, 0);                                                           \
        BAR();                                                                            \
        __builtin_amdgcn_s_setprio(1);                                                    \
        _Pragma("unroll") for (int i = 0; i < 4; ++i)                                     \
            _Pragma("unroll") for (int j = 2; j < 4; ++j) {                               \
                acc[i + 4][j] = __builtin_amdgcn_mfma_f32_16x16x32_bf16(a[i][0], b[j][0], acc[i + 4][j], 0, 0, 0); \
                acc[i + 4][j] = __builtin_amdgcn_mfma_f32_16x16x32_bf16(a[i][1], b[j][1], acc[i + 4][j], 0, 0, 0); \
            }                                                                             \
        __builtin_amdgcn_s_setprio(0);                                                    \
        BAR();                                                                            \
        STAGE(t & 1, u2, 1, 1);                                                           \
        BAR();                                                                            \
        __builtin_amdgcn_s_setprio(1);                                                    \
        _Pragma("unroll") for (int i = 0; i < 4; ++i)                                     \
            _Pragma("unroll") for (int j = 0; j < 2; ++j) {                               \
                acc[i + 4][j] = __builtin_amdgcn_mfma_f32_16x16x32_bf16(a[i][0], b[j][0], acc[i + 4][j], 0, 0, 0); \
                acc[i + 4][j] = __builtin_amdgcn_mfma_f32_16x16x32_bf16(a[i][1], b[j][1], acc[i + 4][j], 0, 0, 0); \
            }                                                                             \
        __builtin_amdgcn_s_setprio(0);                                                    \
        asm volatile("s_waitcnt vmcnt(4)" ::: "memory");                                  \
        BAR();                                                                            \
    }

// ---------------- GEMM1: qkv = xb @ wT^T, fused RoPE + fused V-transpose ----------------

__global__ __launch_bounds__(512, 2) void gemm_qkv_rope(
    const unsigned short* __restrict__ xb,   // ROWS x M_
    const unsigned short* __restrict__ wT,   // CQKV x M_
    unsigned short* __restrict__ qg,         // (B,H,S,D)
    unsigned short* __restrict__ kg,         // (B,H,S,D)
    unsigned short* __restrict__ vt) {       // (B,H,D,S)  <- V written TRANSPOSED
    __shared__ unsigned short lds[65536];    // 128 KiB

    const int tid = threadIdx.x;
    const int lane = tid & 63;
    const int w = tid >> 6;
    const int wr = w >> 2;
    const int wc = w & 3;
    const int lcol = lane & 15;
    const int lq = lane >> 4;

    // T1: XCD swizzle (768 blocks, 768 % 8 == 0)
    const int lin = (int)(blockIdx.y * gridDim.x + blockIdx.x);
    const int swz = (lin & 7) * 96 + (lin >> 3);
    const int r0 = (swz / 24) * BM2;
    const int c0 = (swz % 24) * BN2;

    const unsigned short* Ag = xb;
    const unsigned short* Bg = wT;

    GEMM_MAIN_LOOP()

    // ---- epilogue: RoPE in registers, direct stores (fire-and-forget).
    const int colbase = c0 + wc * 64;
    const int tix = colbase >> 11;
    const int hh = (colbase & 2047) >> 7;
    if (tix < 2) {
        unsigned short* dst = (tix == 0) ? qg : kg;
#pragma unroll
        for (int j = 0; j < 4; ++j) {
            const int d = (wc & 1) * 64 + j * 16 + lcol;
            float inv_ts = exp2f(-(float)(d >> 1) * (13.28771237954945f / 64.0f));
            float sw, cw;
            __sincosf(inv_ts, &sw, &cw);          // rotation step for delta_s = 1
#pragma unroll
            for (int i = 0; i < 8; ++i) {
                int row0 = r0 + wr * 128 + i * 16 + lq * 4;
                int bb = row0 >> 11, s0 = row0 & 2047;   // no wrap within 4 rows
                float sn, cs;
                __sincosf((float)s0 * inv_ts, &sn, &cs);
                size_t base = (size_t)((bb * H_ + hh) * S_ + s0) * D_ + d;
#pragma unroll
                for (int r = 0; r < 4; ++r) {
                    float val = acc[i][j][r];
                    float pr = __shfl_xor(val, 1);
                    float v2 = (d & 1) ? (val * cs + pr * sn) : (val * cs - pr * sn);
                    dst[base + (size_t)r * D_] = f2bf(v2);
                    float ns = sn * cw + cs * sw;
                    float nc = cs * cw - sn * sw;
                    sn = ns; cs = nc;
                }
            }
        }
    } else {
#pragma unroll
        for (int j = 0; j < 4; ++j) {
            const int d = (wc & 1) * 64 + j * 16 + lcol;
#pragma unroll
            for (int i = 0; i < 8; ++i) {
                int row0 = r0 + wr * 128 + i * 16 + lq * 4;
                int bb = row0 >> 11, s0 = row0 & 2047;
                u16x4 v4 = { f2bf(acc[i][j][0]), f2bf(acc[i][j][1]),
                             f2bf(acc[i][j][2]), f2bf(acc[i][j][3]) };
                *(u16x4*)&vt[(size_t)((bb * H_ + hh) * D_ + d) * S_ + s0] = v4;
            }
        }
    }
}

// ---------------- GEMM3: out = ctx @ Wo (256^2 8-phase) ----------------

__global__ __launch_bounds__(512, 2) void gemm_out(
    const unsigned short* __restrict__ ctx,  // ROWS x M_
    const unsigned short* __restrict__ woT,  // M_ x M_
    float* __restrict__ out) {
    __shared__ unsigned short lds[65536];    // 128 KiB

    const int tid = threadIdx.x;
    const int lane = tid & 63;
    const int w = tid >> 6;
    const int wr = w >> 2;
    const int wc = w & 3;
    const int lcol = lane & 15;
    const int lq = lane >> 4;

    // T1: XCD swizzle (256 blocks, 256 % 8 == 0)
    const int lin = (int)(blockIdx.y * gridDim.x + blockIdx.x);
    const int swz = (lin & 7) * 32 + (lin >> 3);
    const int r0 = (swz >> 3) * BM2;
    const int c0 = (swz & 7) * BN2;

    const unsigned short* Ag = ctx;
    const unsigned short* Bg = woT;

    GEMM_MAIN_LOOP()

    // ---- epilogue: f32 direct stores (64B segments, adequate)
#pragma unroll
    for (int i = 0; i < 8; ++i) {
#pragma unroll
        for (int r = 0; r < 4; ++r) {
            int row = r0 + wr * 128 + i * 16 + lq * 4 + r;
#pragma unroll
            for (int j = 0; j < 4; ++j) {
                int col = c0 + wc * 64 + j * 16 + lcol;
                out[(size_t)row * M_ + col] = acc[i][j][r];
            }
        }
    }
}

#undef STAGE
#undef BAR

// ---------------- flash attention (causal, fixed-max softmax) ----------------
// 4 waves x 32 q-rows per 128-row q-tile; 256 threads; 2 blocks/CU.
// NEW vs R5: (a) Ks/VTs double-buffered -> ONE barrier per KV tile; per tile:
//   issue t+1 global loads (top) -> compute cur -> ds_write t+1 into buf^1 ->
//   barrier.  Write-after-read safe: buf^1 readers finished before the barrier
//   at end of tile t-1.  (b) LDS unpadded + T2 XOR swizzle (chunk ^= row&15
//   for Ks, ^= row&7 for VTs/Ps) -> all b128 reads bank-conflict-free, and
//   LDS = 2*16 + 2*16 + 16 = 80 KB = exactly 2 blocks/CU.

__global__ __launch_bounds__(256, 2) void attn(
    const unsigned short* __restrict__ qg,
    const unsigned short* __restrict__ kg,
    const unsigned short* __restrict__ vt,   // (B,H,D,S)
    unsigned short* __restrict__ ctx) {
    __shared__ unsigned short Ks[2][64 * 128];   // (s,d) swizzled, dbuf
    __shared__ unsigned short VTs[2][128 * 64];  // (d,s) swizzled, dbuf
    __shared__ unsigned short Ps[128 * 64];      // per-wave-private, swizzled

    const int tid = threadIdx.x, lane = tid & 63, wave = tid >> 6;  // wave 0..3

    // T1: XCD swizzle (1024 blocks): 8 heads x 16 q-tiles per XCD, heavy first
    const int lin = (int)(blockIdx.y * gridDim.x + blockIdx.x);
    const int idx = lin >> 3;
    const int bh = ((lin & 7) << 3) + (idx >> 4);
    const int q0 = (15 - (idx & 15)) * 128;
    const int q0w = q0 + wave * 32;
    const unsigned short* qb = qg + (size_t)bh * S_ * D_;
    const unsigned short* kb = kg + (size_t)bh * S_ * D_;
    const unsigned short* vtb = vt + (size_t)bh * S_ * D_;

    const int lcol = lane & 15;
    const int lq = lane >> 4;

    const float scale = 0.08838834764831845f;
    bf16x8 qf[2][4];
#pragma unroll
    for (int f = 0; f < 2; ++f)
#pragma unroll
        for (int kk = 0; kk < 4; ++kk) {
            u16x8 raw = *(const u16x8*)&qb[(size_t)(q0w + f * 16 + lcol) * D_ + kk * 32 + lq * 8];
            u16x8 sc8;
#pragma unroll
            for (int j = 0; j < 8; ++j) sc8[j] = f2bf(bf2f(raw[j]) * scale);
            qf[f][kk] = __builtin_bit_cast(bf16x8, sc8);
        }

    f32x4 o[2][8];
#pragma unroll
    for (int f = 0; f < 2; ++f)
#pragma unroll
        for (int ot = 0; ot < 8; ++ot) o[f][ot] = (f32x4){0.f, 0.f, 0.f, 0.f};
    float lsum[2][4] = {{0.f, 0.f, 0.f, 0.f}, {0.f, 0.f, 0.f, 0.f}};

    const int kv_last = q0 + 64;   // covers q rows up to q0+127

    // staging swizzle (write side): K chunk c&15 ^ row&15; VT chunk c&7 ^ row&7
    // (reg-staged writes -> both-sides swizzle, rule #21 satisfied)
    u16x8 kpre[4], vpre[4];
#pragma unroll
    for (int j = 0; j < 4; ++j) {
        int c = tid + j * 256;
        kpre[j] = *(const u16x8*)&kb[(size_t)(c >> 4) * D_ + (c & 15) * 8];
        vpre[j] = *(const u16x8*)&vtb[(size_t)(c >> 3) * S_ + (c & 7) * 8];
    }
#pragma unroll
    for (int j = 0; j < 4; ++j) {
        int c = tid + j * 256;
        *(u16x8*)&Ks[0][(c >> 4) * 128 + (((c & 15) ^ ((c >> 4) & 15)) * 8)] = kpre[j];
        *(u16x8*)&VTs[0][(c >> 3) * 64 + (((c & 7) ^ ((c >> 3) & 7)) * 8)] = vpre[j];
    }
    __syncthreads();

    for (int kv0 = 0; kv0 <= kv_last; kv0 += 64) {
        const int cur = (kv0 >> 6) & 1;
        const bool more = (kv0 + 64 <= kv_last);

        // issue next-tile global loads NOW; compute phase hides HBM latency (T14)
        if (more) {
#pragma unroll
            for (int j = 0; j < 4; ++j) {
                int c = tid + j * 256;
                kpre[j] = *(const u16x8*)&kb[(size_t)(kv0 + 64 + (c >> 4)) * D_ + (c & 15) * 8];
                vpre[j] = *(const u16x8*)&vtb[(size_t)(c >> 3) * S_ + kv0 + 64 + (c & 7) * 8];
            }
        }

        if (kv0 <= q0w + 31) {                 // wave-uniform skip above diagonal
            // S = Q K^T : 32 x 64 per wave, kf shared across both q-fragments
            f32x4 sc[2][4];
            __builtin_amdgcn_s_setprio(1);
#pragma unroll
            for (int nt = 0; nt < 4; ++nt) {
                f32x4 a0 = (f32x4){0.f, 0.f, 0.f, 0.f};
                f32x4 a1 = (f32x4){0.f, 0.f, 0.f, 0.f};
#pragma unroll
                for (int kk = 0; kk < 4; ++kk) {
                    bf16x8 kf = *(const bf16x8*)&Ks[cur][(nt * 16 + lcol) * 128 + (((kk * 4 + lq) ^ lcol) * 8)];
                    a0 = __builtin_amdgcn_mfma_f32_16x16x32_bf16(qf[0][kk], kf, a0, 0, 0, 0);
                    a1 = __builtin_amdgcn_mfma_f32_16x16x32_bf16(qf[1][kk], kf, a1, 0, 0, 0);
                }
                sc[0][nt] = a0; sc[1][nt] = a1;
            }
            __builtin_amdgcn_s_setprio(0);

#pragma unroll
            for (int f = 0; f < 2; ++f) {
                if (kv0 + 63 > q0w + f * 16) {     // diagonal: mask
#pragma unroll
                    for (int nt = 0; nt < 4; ++nt)
#pragma unroll
                        for (int r = 0; r < 4; ++r) {
                            int skv = kv0 + nt * 16 + lcol;
                            int sq = q0w + f * 16 + lq * 4 + r;
                            float p = (skv > sq) ? 0.f : __expf(sc[f][nt][r]);
                            sc[f][nt][r] = p;
                            lsum[f][r] += p;
                        }
                } else {
#pragma unroll
                    for (int nt = 0; nt < 4; ++nt)
#pragma unroll
                        for (int r = 0; r < 4; ++r) {
                            float p = __expf(sc[f][nt][r]);
                            sc[f][nt][r] = p;
                            lsum[f][r] += p;
                        }
                }
                // P: C-layout -> wave-private LDS slab (same-wave DS in-order)
                // swizzled: row = wave*32+f*16+lq*4+r, chunk = nt*2+(lcol>>3) ^ row&7
#pragma unroll
                for (int nt = 0; nt < 4; ++nt)
#pragma unroll
                    for (int r = 0; r < 4; ++r) {
                        int prow = wave * 32 + f * 16 + lq * 4 + r;
                        int pch = (nt * 2 + (lcol >> 3)) ^ (prow & 7);
                        Ps[prow * 64 + pch * 8 + (lcol & 7)] = f2bf(sc[f][nt][r]);
                    }
            }

            __builtin_amdgcn_s_setprio(1);
#pragma unroll
            for (int kk = 0; kk < 2; ++kk) {
                int pxor = ((kk * 4 + lq) ^ (lcol & 7)) * 8;
                bf16x8 pf0 = *(const bf16x8*)&Ps[(wave * 32 + lcol) * 64 + pxor];
                bf16x8 pf1 = *(const bf16x8*)&Ps[(wave * 32 + 16 + lcol) * 64 + pxor];
#pragma unroll
                for (int ot = 0; ot < 8; ++ot) {
                    bf16x8 vf = *(const bf16x8*)&VTs[cur][(ot * 16 + lcol) * 64 + pxor];
                    o[0][ot] = __builtin_amdgcn_mfma_f32_16x16x32_bf16(pf0, vf, o[0][ot], 0, 0, 0);
                    o[1][ot] = __builtin_amdgcn_mfma_f32_16x16x32_bf16(pf1, vf, o[1][ot], 0, 0, 0);
                }
            }
            __builtin_amdgcn_s_setprio(0);
        }

        // write next tile into the other buffer (compiler waits vmcnt on kpre/vpre)
        if (more) {
#pragma unroll
            for (int j = 0; j < 4; ++j) {
                int c = tid + j * 256;
                *(u16x8*)&Ks[cur ^ 1][(c >> 4) * 128 + (((c & 15) ^ ((c >> 4) & 15)) * 8)] = kpre[j];
                *(u16x8*)&VTs[cur ^ 1][(c >> 3) * 64 + (((c & 7) ^ ((c >> 3) & 7)) * 8)] = vpre[j];
            }
        }
        __syncthreads();                       // ONE barrier per KV tile
    }

    // final l reduction across the 16 lanes sharing lq
#pragma unroll
    for (int f = 0; f < 2; ++f)
#pragma unroll
        for (int r = 0; r < 4; ++r) {
#pragma unroll
            for (int off = 1; off < 16; off <<= 1) lsum[f][r] += __shfl_xor(lsum[f][r], off);
        }

    // epilogue -> ctx (B,S,H*D) bf16
    const int b = bh >> 4, h = bh & 15;
#pragma unroll
    for (int f = 0; f < 2; ++f)
#pragma unroll
        for (int r = 0; r < 4; ++r) {
            float invl = 1.0f / lsum[f][r];
            int s = q0w + f * 16 + lq * 4 + r;
#pragma unroll
            for (int ot = 0; ot < 8; ++ot) {
                int d = ot * 16 + lcol;
                ctx[(size_t)(b * S_ + s) * (H_ * D_) + h * D_ + d] = f2bf(o[f][ot][r] * invl);
            }
        }
}

// ---------------- launch ----------------

extern "C" void kernel_launch(void* const* d_in, const int* in_sizes, int n_in,
                              void* d_out, int out_size, void* d_ws, size_t ws_size,
                              hipStream_t stream) {
    const float* x = (const float*)d_in[0];
    const float* Wqkv = (const float*)d_in[1];
    const float* Wo = (const float*)d_in[2];
    float* out = (float*)d_out;

    unsigned short* xb = (unsigned short*)d_ws;                 // ROWS x M_
    unsigned short* wT = xb + (size_t)ROWS * M_;                // CQKV x M_
    unsigned short* woT = wT + (size_t)CQKV * M_;               // M_ x M_
    unsigned short* qg = woT + (size_t)M_ * M_;                 // B,H,S,D
    unsigned short* kg = qg + (size_t)B_ * H_ * S_ * D_;
    unsigned short* vtw = kg + (size_t)B_ * H_ * S_ * D_;       // B,H,D,S (written by gemm_qkv)
    unsigned short* ctxp = vtw + (size_t)B_ * H_ * S_ * D_;     // ROWS x M_

    cvt_bf16<<<(ROWS * M_) / 1024, 256, 0, stream>>>(x, xb);
    cvt_transpose<<<dim3(CQKV / 32, M_ / 32), dim3(32, 8), 0, stream>>>(Wqkv, wT, M_, CQKV);
    cvt_transpose<<<dim3(M_ / 32, M_ / 32), dim3(32, 8), 0, stream>>>(Wo, woT, M_, M_);

    gemm_qkv_rope<<<dim3(CQKV / BN2, ROWS / BM2), 512, 0, stream>>>(xb, wT, qg, kg, vtw);
    attn<<<dim3(S_ / 128, B_ * H_), 256, 0, stream>>>(qg, kg, vtw, ctxp);
    gemm_out<<<dim3(M_ / BN2, ROWS / BM2), 512, 0, stream>>>(ctxp, woT, out);
}

// Round 7
// 555.613 us; speedup vs baseline: 1.0584x; 1.0584x over previous
//
#include <hip/hip_runtime.h>
#include <hip/hip_bf16.h>

#define B_ 4
#define S_ 2048
#define M_ 2048
#define H_ 16
#define D_ 128
#define ROWS (B_*S_)      // 8192
#define CQKV (3*H_*D_)    // 6144

typedef __bf16 bf16x8 __attribute__((ext_vector_type(8)));
typedef float f32x4 __attribute__((ext_vector_type(4)));
typedef unsigned short u16x8 __attribute__((ext_vector_type(8)));
typedef unsigned short u16x4 __attribute__((ext_vector_type(4)));
typedef short s16x4 __attribute__((ext_vector_type(4)));

__device__ __forceinline__ unsigned short f2bf(float x) {
    unsigned u = __builtin_bit_cast(unsigned, x);
    u += 0x7fffu + ((u >> 16) & 1u);   // RNE
    return (unsigned short)(u >> 16);
}
__device__ __forceinline__ float bf2f(unsigned short u) {
    return __builtin_bit_cast(float, (unsigned)u << 16);
}

// async global->LDS, 16B per lane; LDS dest = base + lane*16 (wave-uniform base)
__device__ __forceinline__ void gld_lds16(const unsigned short* g, unsigned short* l) {
    __builtin_amdgcn_global_load_lds(
        (__attribute__((address_space(1))) void*)g,
        (__attribute__((address_space(3))) void*)l,
        16, 0, 0);
}

// ---------------- conversion kernels ----------------

__global__ __launch_bounds__(256) void cvt_bf16(const float* __restrict__ in,
                                                unsigned short* __restrict__ out) {
    int idx = (blockIdx.x * 256 + threadIdx.x) * 4;
    float4 v = *(const float4*)&in[idx];
    u16x4 o = { f2bf(v.x), f2bf(v.y), f2bf(v.z), f2bf(v.w) };
    *(u16x4*)&out[idx] = o;
}

// out[c*R + r] = bf16(in[r*C + c]);  grid = (C/32, R/32), block = (32,8)
__global__ __launch_bounds__(256) void cvt_transpose(const float* __restrict__ in,
                                                     unsigned short* __restrict__ out,
                                                     int R, int C) {
    __shared__ unsigned short tile[32][33];
    int c0 = blockIdx.x * 32, r0 = blockIdx.y * 32;
    int tx = threadIdx.x, ty = threadIdx.y;
#pragma unroll
    for (int i = 0; i < 4; ++i)
        tile[ty + i * 8][tx] = f2bf(in[(size_t)(r0 + ty + i * 8) * C + c0 + tx]);
    __syncthreads();
#pragma unroll
    for (int i = 0; i < 4; ++i)
        out[(size_t)(c0 + ty + i * 8) * R + r0 + tx] = tile[tx][ty + i * 8];
}

// ---------------- 256x256/BK64 8-phase GEMM core (T1+T2+T3+T4+T5) ----------------
// LDS: 2 buffers x (A[256][64] + B[256][64]) bf16 = 128 KiB.
// Staging: Ah0(u)@[u-1,A], Ah1(u)@[u-1,B], Bh0(u)@[u-2,C], Bh1(u)@[u-2,D];
// counted vmcnt(4) once per tile.  T2: chunk ^= row&7 via inverse-swizzled
// global source (linear LDS dest) + swizzled ds_read.

#define BM2 256
#define BN2 256
#define BK2 64
#define NT2 (M_/BK2)   // 32

#define STAGE(p_, u_, mat_, h_) do {                                                     \
        const unsigned short* _s = (mat_) ? Bg : Ag;                                     \
        const size_t _r = (size_t)((((mat_) ? c0 : r0) + (h_) * 128) + w * 8 + srow) * M_ \
                          + (u_) * BK2 + scol;                                           \
        unsigned short* _l = &lds[(p_) * 32768 + (mat_) * 16384 + (h_) * 8192 + w * 512]; \
        gld_lds16(&_s[_r], _l);                                                          \
        gld_lds16(&_s[_r + (size_t)64 * M_], _l + 4096);                                 \
    } while (0)

#define BAR() asm volatile("s_barrier" ::: "memory")

#define GEMM_MAIN_LOOP()                                                                  \
    const int srow = lane >> 3;                                                           \
    const int scol = ((lane & 7) ^ srow) * 8;                                             \
    const int axor = lcol & 7;                                                            \
    const int k0off = (lq ^ axor) * 8;                                                    \
    const int k1off = ((4 | lq) ^ axor) * 8;                                              \
    const int arow = wr * 8192 + lcol * 64;                                               \
    const int brow = 16384 + (wc >> 1) * 8192 + ((wc & 1) * 64 + lcol) * 64;              \
    f32x4 acc[8][4];                                                                      \
    _Pragma("unroll") for (int i = 0; i < 8; ++i)                                         \
        _Pragma("unroll") for (int j = 0; j < 4; ++j) acc[i][j] = (f32x4){0.f,0.f,0.f,0.f};\
    STAGE(0, 0, 0, 0); STAGE(0, 0, 0, 1); STAGE(0, 0, 1, 0); STAGE(0, 0, 1, 1);           \
    STAGE(1, 1, 1, 0); STAGE(1, 1, 1, 1);                                                 \
    asm volatile("s_waitcnt vmcnt(4)" ::: "memory");                                      \
    BAR();                                                                                \
    bf16x8 a[4][2], b[4][2];                                                              \
    for (int t = 0; t < NT2; ++t) {                                                       \
        const int bo = (t & 1) * 32768;                                                   \
        const int pn = (t + 1) & 1;                                                       \
        const int u1 = (t + 1 < NT2) ? (t + 1) : (NT2 - 1);                               \
        const int u2 = (t + 2 < NT2) ? (t + 2) : (NT2 - 1);                               \
        _Pragma("unroll") for (int i = 0; i < 4; ++i) {                                   \
            a[i][0] = *(const bf16x8*)&lds[bo + arow + i * 1024 + k0off];                  \
            a[i][1] = *(const bf16x8*)&lds[bo + arow + i * 1024 + k1off];                  \
        }                                                                                 \
        _Pragma("unroll") for (int j = 0; j < 2; ++j) {                                   \
            b[j][0] = *(const bf16x8*)&lds[bo + brow + j * 1024 + k0off];                  \
            b[j][1] = *(const bf16x8*)&lds[bo + brow + j * 1024 + k1off];                  \
        }                                                                                 \
        STAGE(pn, u1, 0, 0);                                                              \
        BAR();                                                                            \
        __builtin_amdgcn_s_setprio(1);                                                    \
        _Pragma("unroll") for (int i = 0; i < 4; ++i)                                     \
            _Pragma("unroll") for (int j = 0; j < 2; ++j) {                               \
                acc[i][j] = __builtin_amdgcn_mfma_f32_16x16x32_bf16(a[i][0], b[j][0], acc[i][j], 0, 0, 0); \
                acc[i][j] = __builtin_amdgcn_mfma_f32_16x16x32_bf16(a[i][1], b[j][1], acc[i][j], 0, 0, 0); \
            }                                                                             \
        __builtin_amdgcn_s_setprio(0);                                                    \
        BAR();                                                                            \
        _Pragma("unroll") for (int j = 2; j < 4; ++j) {                                   \
            b[j][0] = *(const bf16x8*)&lds[bo + brow + j * 1024 + k0off];                  \
            b[j][1] = *(const bf16x8*)&lds[bo + brow + j * 1024 + k1off];                  \
        }                                                                                 \
        STAGE(pn, u1, 0, 1);                                                              \
        BAR();                                                                            \
        __builtin_amdgcn_s_setprio(1);                                                    \
        _Pragma("unroll") for (int i = 0; i < 4; ++i)                                     \
            _Pragma("unroll") for (int j = 2; j < 4; ++j) {                               \
                acc[i][j] = __builtin_amdgcn_mfma_f32_16x16x32_bf16(a[i][0], b[j][0], acc[i][j], 0, 0, 0); \
                acc[i][j] = __builtin_amdgcn_mfma_f32_16x16x32_bf16(a[i][1], b[j][1], acc[i][j], 0, 0, 0); \
            }                                                                             \
        __builtin_amdgcn_s_setprio(0);                                                    \
        BAR();                                                                            \
        _Pragma("unroll") for (int i = 0; i < 4; ++i) {                                   \
            a[i][0] = *(const bf16x8*)&lds[bo + arow + (i + 4) * 1024 + k0off];            \
            a[i][1] = *(const bf16x8*)&lds[bo + arow + (i + 4) * 1024 + k1off];            \
        }                                                                                 \
        STAGE(t & 1, u2, 1, 0);                                                           \
        BAR();                                                                            \
        __builtin_amdgcn_s_setprio(1);                                                    \
        _Pragma("unroll") for (int i = 0; i < 4; ++i)                                     \
            _Pragma("unroll") for (int j = 2; j < 4; ++j) {                               \
                acc[i + 4][j] = __builtin_amdgcn_mfma_f32_16x16x32_bf16(a[i][0], b[j][0], acc[i + 4][j], 0, 0, 0); \
                acc[i + 4][j] = __builtin_amdgcn_mfma_f32_16x16x32_bf16(a[i][1], b[j][1], acc[i + 4][j], 0, 0, 0); \
            }                                                                             \
        __builtin_amdgcn_s_setprio(0);                                                    \
        BAR();                                                                            \
        STAGE(t & 1, u2, 1, 1);                                                           \
        BAR();                                                                            \
        __builtin_amdgcn_s_setprio(1);                                                    \
        _Pragma("unroll") for (int i = 0; i < 4; ++i)                                     \
            _Pragma("unroll") for (int j = 0; j < 2; ++j) {                               \
                acc[i + 4][j] = __builtin_amdgcn_mfma_f32_16x16x32_bf16(a[i][0], b[j][0], acc[i + 4][j], 0, 0, 0); \
                acc[i + 4][j] = __builtin_amdgcn_mfma_f32_16x16x32_bf16(a[i][1], b[j][1], acc[i + 4][j], 0, 0, 0); \
            }                                                                             \
        __builtin_amdgcn_s_setprio(0);                                                    \
        asm volatile("s_waitcnt vmcnt(4)" ::: "memory");                                  \
        BAR();                                                                            \
    }

// ---------------- GEMM1: qkv = xb @ wT^T, fused RoPE + fused V-transpose ----------------

__global__ __launch_bounds__(512, 2) void gemm_qkv_rope(
    const unsigned short* __restrict__ xb,   // ROWS x M_
    const unsigned short* __restrict__ wT,   // CQKV x M_
    unsigned short* __restrict__ qg,         // (B,H,S,D)
    unsigned short* __restrict__ kg,         // (B,H,S,D)
    unsigned short* __restrict__ vt) {       // (B,H,D,S)  <- V written TRANSPOSED
    __shared__ unsigned short lds[65536];    // 128 KiB

    const int tid = threadIdx.x;
    const int lane = tid & 63;
    const int w = tid >> 6;
    const int wr = w >> 2;
    const int wc = w & 3;
    const int lcol = lane & 15;
    const int lq = lane >> 4;

    // T1: XCD swizzle (768 blocks, 768 % 8 == 0)
    const int lin = (int)(blockIdx.y * gridDim.x + blockIdx.x);
    const int swz = (lin & 7) * 96 + (lin >> 3);
    const int r0 = (swz / 24) * BM2;
    const int c0 = (swz % 24) * BN2;

    const unsigned short* Ag = xb;
    const unsigned short* Bg = wT;

    GEMM_MAIN_LOOP()

    // ---- epilogue: RoPE in registers, direct stores (fire-and-forget).
    const int colbase = c0 + wc * 64;
    const int tix = colbase >> 11;
    const int hh = (colbase & 2047) >> 7;
    if (tix < 2) {
        unsigned short* dst = (tix == 0) ? qg : kg;
#pragma unroll
        for (int j = 0; j < 4; ++j) {
            const int d = (wc & 1) * 64 + j * 16 + lcol;
            float inv_ts = exp2f(-(float)(d >> 1) * (13.28771237954945f / 64.0f));
            float sw, cw;
            __sincosf(inv_ts, &sw, &cw);          // rotation step for delta_s = 1
#pragma unroll
            for (int i = 0; i < 8; ++i) {
                int row0 = r0 + wr * 128 + i * 16 + lq * 4;
                int bb = row0 >> 11, s0 = row0 & 2047;   // no wrap within 4 rows
                float sn, cs;
                __sincosf((float)s0 * inv_ts, &sn, &cs);
                size_t base = (size_t)((bb * H_ + hh) * S_ + s0) * D_ + d;
#pragma unroll
                for (int r = 0; r < 4; ++r) {
                    float val = acc[i][j][r];
                    float pr = __shfl_xor(val, 1);
                    float v2 = (d & 1) ? (val * cs + pr * sn) : (val * cs - pr * sn);
                    dst[base + (size_t)r * D_] = f2bf(v2);
                    float ns = sn * cw + cs * sw;
                    float nc = cs * cw - sn * sw;
                    sn = ns; cs = nc;
                }
            }
        }
    } else {
#pragma unroll
        for (int j = 0; j < 4; ++j) {
            const int d = (wc & 1) * 64 + j * 16 + lcol;
#pragma unroll
            for (int i = 0; i < 8; ++i) {
                int row0 = r0 + wr * 128 + i * 16 + lq * 4;
                int bb = row0 >> 11, s0 = row0 & 2047;
                u16x4 v4 = { f2bf(acc[i][j][0]), f2bf(acc[i][j][1]),
                             f2bf(acc[i][j][2]), f2bf(acc[i][j][3]) };
                *(u16x4*)&vt[(size_t)((bb * H_ + hh) * D_ + d) * S_ + s0] = v4;
            }
        }
    }
}

// ---------------- GEMM3: out = ctx @ Wo (256^2 8-phase) ----------------

__global__ __launch_bounds__(512, 2) void gemm_out(
    const unsigned short* __restrict__ ctx,  // ROWS x M_
    const unsigned short* __restrict__ woT,  // M_ x M_
    float* __restrict__ out) {
    __shared__ unsigned short lds[65536];    // 128 KiB

    const int tid = threadIdx.x;
    const int lane = tid & 63;
    const int w = tid >> 6;
    const int wr = w >> 2;
    const int wc = w & 3;
    const int lcol = lane & 15;
    const int lq = lane >> 4;

    // T1: XCD swizzle (256 blocks, 256 % 8 == 0)
    const int lin = (int)(blockIdx.y * gridDim.x + blockIdx.x);
    const int swz = (lin & 7) * 32 + (lin >> 3);
    const int r0 = (swz >> 3) * BM2;
    const int c0 = (swz & 7) * BN2;

    const unsigned short* Ag = ctx;
    const unsigned short* Bg = woT;

    GEMM_MAIN_LOOP()

    // ---- epilogue: f32 direct stores (64B segments, adequate)
#pragma unroll
    for (int i = 0; i < 8; ++i) {
#pragma unroll
        for (int r = 0; r < 4; ++r) {
            int row = r0 + wr * 128 + i * 16 + lq * 4 + r;
#pragma unroll
            for (int j = 0; j < 4; ++j) {
                int col = c0 + wc * 64 + j * 16 + lcol;
                out[(size_t)row * M_ + col] = acc[i][j][r];
            }
        }
    }
}

#undef STAGE
#undef BAR

// ---------------- flash attention (causal, fixed-max softmax) ----------------
// R5 skeleton (proven best): 4 waves x 32 q-rows, 256 threads, padded LDS,
// 2-barrier staging, register prefetch, 2 blocks/CU.
// NEW: swapped QK^T (mfma(kf,qf)) so each lane holds P[q=lcol][kv=nt*16+lq*4+r]
// -> exactly the A-fragment of mfma_f32_16x16x16_bf16 (k-slot = lq*4+e).
// PV runs 4x K=16 MFMAs per ot with P packed IN REGISTERS: the Ps LDS buffer,
// 32 ds_write_b16 and 4 ds_read_b128 per tile (and their same-wave in-order
// drain on the critical path) are deleted.  V reads become b64 (same bytes,
// same 2-way-free bank pattern).  lsum: scalar per lane (q=lcol), reduced with
// 2 shfl_xor; epilogue redistributes via 8 shfls.

__global__ __launch_bounds__(256, 2) void attn(
    const unsigned short* __restrict__ qg,
    const unsigned short* __restrict__ kg,
    const unsigned short* __restrict__ vt,   // (B,H,D,S)
    unsigned short* __restrict__ ctx) {
    __shared__ unsigned short Ks[64 * 136];   // (s,d) padded
    __shared__ unsigned short VTs[128 * 72];  // (d,s) padded

    const int tid = threadIdx.x, lane = tid & 63, wave = tid >> 6;  // wave 0..3

    // T1: XCD swizzle (1024 blocks): 8 heads x 16 q-tiles per XCD, heavy first
    const int lin = (int)(blockIdx.y * gridDim.x + blockIdx.x);
    const int idx = lin >> 3;
    const int bh = ((lin & 7) << 3) + (idx >> 4);
    const int q0 = (15 - (idx & 15)) * 128;
    const int q0w = q0 + wave * 32;
    const unsigned short* qb = qg + (size_t)bh * S_ * D_;
    const unsigned short* kb = kg + (size_t)bh * S_ * D_;
    const unsigned short* vtb = vt + (size_t)bh * S_ * D_;

    const int lcol = lane & 15;
    const int lq = lane >> 4;

    const float scale = 0.08838834764831845f;
    bf16x8 qf[2][4];
#pragma unroll
    for (int f = 0; f < 2; ++f)
#pragma unroll
        for (int kk = 0; kk < 4; ++kk) {
            u16x8 raw = *(const u16x8*)&qb[(size_t)(q0w + f * 16 + lcol) * D_ + kk * 32 + lq * 8];
            u16x8 sc8;
#pragma unroll
            for (int j = 0; j < 8; ++j) sc8[j] = f2bf(bf2f(raw[j]) * scale);
            qf[f][kk] = __builtin_bit_cast(bf16x8, sc8);
        }

    f32x4 o[2][8];
#pragma unroll
    for (int f = 0; f < 2; ++f)
#pragma unroll
        for (int ot = 0; ot < 8; ++ot) o[f][ot] = (f32x4){0.f, 0.f, 0.f, 0.f};
    float lsum[2] = {0.f, 0.f};

    const int kv_last = q0 + 64;   // covers q rows up to q0+127

    // register prefetch of tile 0 (256 threads x 4 chunks each for K and VT)
    u16x8 kpre[4], vpre[4];
#pragma unroll
    for (int j = 0; j < 4; ++j) {
        int c = tid + j * 256;
        kpre[j] = *(const u16x8*)&kb[(size_t)(c >> 4) * D_ + (c & 15) * 8];
        vpre[j] = *(const u16x8*)&vtb[(size_t)(c >> 3) * S_ + (c & 7) * 8];
    }

    for (int kv0 = 0; kv0 <= kv_last; kv0 += 64) {
        __syncthreads();                       // prior reads of Ks/VTs done
#pragma unroll
        for (int j = 0; j < 4; ++j) {
            int c = tid + j * 256;
            *(u16x8*)&Ks[(c >> 4) * 136 + (c & 15) * 8] = kpre[j];
            *(u16x8*)&VTs[(c >> 3) * 72 + (c & 7) * 8] = vpre[j];
        }
        __syncthreads();                       // staging visible
        if (kv0 + 64 <= kv_last) {             // prefetch next tile (overlaps compute)
#pragma unroll
            for (int j = 0; j < 4; ++j) {
                int c = tid + j * 256;
                kpre[j] = *(const u16x8*)&kb[(size_t)(kv0 + 64 + (c >> 4)) * D_ + (c & 15) * 8];
                vpre[j] = *(const u16x8*)&vtb[(size_t)(c >> 3) * S_ + kv0 + 64 + (c & 7) * 8];
            }
        }

        if (kv0 <= q0w + 31) {                 // wave-uniform skip above diagonal
            // S^T = K Q^T : rows=kv, cols=q; kf shared across both q-fragments
            f32x4 sc[2][4];
            __builtin_amdgcn_s_setprio(1);
#pragma unroll
            for (int nt = 0; nt < 4; ++nt) {
                f32x4 a0 = (f32x4){0.f, 0.f, 0.f, 0.f};
                f32x4 a1 = (f32x4){0.f, 0.f, 0.f, 0.f};
#pragma unroll
                for (int kk = 0; kk < 4; ++kk) {
                    bf16x8 kf = *(const bf16x8*)&Ks[(nt * 16 + lcol) * 136 + kk * 32 + lq * 8];
                    a0 = __builtin_amdgcn_mfma_f32_16x16x32_bf16(kf, qf[0][kk], a0, 0, 0, 0);
                    a1 = __builtin_amdgcn_mfma_f32_16x16x32_bf16(kf, qf[1][kk], a1, 0, 0, 0);
                }
                sc[0][nt] = a0; sc[1][nt] = a1;
            }
            __builtin_amdgcn_s_setprio(0);

            // softmax numerator in-register: lane owns q=lcol, kv=nt*16+lq*4+r
            s16x4 pa[2][4];
#pragma unroll
            for (int f = 0; f < 2; ++f) {
                const int sq = q0w + f * 16 + lcol;
                if (kv0 + 63 > sq) {               // diagonal fragment: mask
#pragma unroll
                    for (int nt = 0; nt < 4; ++nt) {
                        u16x4 pk;
#pragma unroll
                        for (int r = 0; r < 4; ++r) {
                            int skv = kv0 + nt * 16 + lq * 4 + r;
                            float p = (skv > sq) ? 0.f : __expf(sc[f][nt][r]);
                            lsum[f] += p;
                            pk[r] = f2bf(p);
                        }
                        pa[f][nt] = __builtin_bit_cast(s16x4, pk);
                    }
                } else {
#pragma unroll
                    for (int nt = 0; nt < 4; ++nt) {
                        u16x4 pk;
#pragma unroll
                        for (int r = 0; r < 4; ++r) {
                            float p = __expf(sc[f][nt][r]);
                            lsum[f] += p;
                            pk[r] = f2bf(p);
                        }
                        pa[f][nt] = __builtin_bit_cast(s16x4, pk);
                    }
                }
            }

            // PV: o[q][d] += P[q][kv] V[kv][d], 4x K=16 MFMA per ot, P in regs
            __builtin_amdgcn_s_setprio(1);
#pragma unroll
            for (int nt = 0; nt < 4; ++nt) {
#pragma unroll
                for (int ot = 0; ot < 8; ++ot) {
                    s16x4 vf = *(const s16x4*)&VTs[(ot * 16 + lcol) * 72 + nt * 16 + lq * 4];
                    o[0][ot] = __builtin_amdgcn_mfma_f32_16x16x16bf16_1k(pa[0][nt], vf, o[0][ot], 0, 0, 0);
                    o[1][ot] = __builtin_amdgcn_mfma_f32_16x16x16bf16_1k(pa[1][nt], vf, o[1][ot], 0, 0, 0);
                }
            }
            __builtin_amdgcn_s_setprio(0);
        }
    }

    // lsum: sum across the 4 lanes sharing lcol (lq dimension)
#pragma unroll
    for (int f = 0; f < 2; ++f) {
        lsum[f] += __shfl_xor(lsum[f], 16);
        lsum[f] += __shfl_xor(lsum[f], 32);
    }

    // epilogue -> ctx (B,S,H*D) bf16; invl for q=lq*4+r lives at lane lq*4+r
    const int b = bh >> 4, h = bh & 15;
#pragma unroll
    for (int f = 0; f < 2; ++f)
#pragma unroll
        for (int r = 0; r < 4; ++r) {
            float lv = __shfl(lsum[f], lq * 4 + r);
            float invl = 1.0f / lv;
            int s = q0w + f * 16 + lq * 4 + r;
#pragma unroll
            for (int ot = 0; ot < 8; ++ot) {
                int d = ot * 16 + lcol;
                ctx[(size_t)(b * S_ + s) * (H_ * D_) + h * D_ + d] = f2bf(o[f][ot][r] * invl);
            }
        }
}

// ---------------- launch ----------------

extern "C" void kernel_launch(void* const* d_in, const int* in_sizes, int n_in,
                              void* d_out, int out_size, void* d_ws, size_t ws_size,
                              hipStream_t stream) {
    const float* x = (const float*)d_in[0];
    const float* Wqkv = (const float*)d_in[1];
    const float* Wo = (const float*)d_in[2];
    float* out = (float*)d_out;

    unsigned short* xb = (unsigned short*)d_ws;                 // ROWS x M_
    unsigned short* wT = xb + (size_t)ROWS * M_;                // CQKV x M_
    unsigned short* woT = wT + (size_t)CQKV * M_;               // M_ x M_
    unsigned short* qg = woT + (size_t)M_ * M_;                 // B,H,S,D
    unsigned short* kg = qg + (size_t)B_ * H_ * S_ * D_;
    unsigned short* vtw = kg + (size_t)B_ * H_ * S_ * D_;       // B,H,D,S (written by gemm_qkv)
    unsigned short* ctxp = vtw + (size_t)B_ * H_ * S_ * D_;     // ROWS x M_

    cvt_bf16<<<(ROWS * M_) / 1024, 256, 0, stream>>>(x, xb);
    cvt_transpose<<<dim3(CQKV / 32, M_ / 32), dim3(32, 8), 0, stream>>>(Wqkv, wT, M_, CQKV);
    cvt_transpose<<<dim3(M_ / 32, M_ / 32), dim3(32, 8), 0, stream>>>(Wo, woT, M_, M_);

    gemm_qkv_rope<<<dim3(CQKV / BN2, ROWS / BM2), 512, 0, stream>>>(xb, wT, qg, kg, vtw);
    attn<<<dim3(S_ / 128, B_ * H_), 256, 0, stream>>>(qg, kg, vtw, ctxp);
    gemm_out<<<dim3(M_ / BN2, ROWS / BM2), 512, 0, stream>>>(ctxp, woT, out);
}